// Round 6
// baseline (379.901 us; speedup 1.0000x reference)
//
#include <hip/hip_runtime.h>
#include <hip/hip_bf16.h>
#include <cstdint>

// Shapes (fixed by the problem)
#define NB 32
#define NS 1024
#define NH 768
#define NP 98

typedef __attribute__((ext_vector_type(8))) short short8;
typedef __attribute__((ext_vector_type(4))) float f32x4;

static __device__ __forceinline__ ushort f2bf(float f) {
  uint32_t u = __builtin_bit_cast(uint32_t, f);
  u += 0x7fff + ((u >> 16) & 1);  // RNE
  return (ushort)(u >> 16);
}
static __device__ __forceinline__ float bf2f(ushort h) {
  uint32_t u = ((uint32_t)h) << 16;
  return __builtin_bit_cast(float, u);
}
// async global->LDS 16B (per-lane global src, wave-uniform LDS base + lane*16)
static __device__ __forceinline__ void gload16(const ushort* g, ushort* l) {
  __builtin_amdgcn_global_load_lds((const __attribute__((address_space(1))) uint32_t*)g,
                                   (__attribute__((address_space(3))) uint32_t*)l, 16, 0, 0);
}

// ---------------------------------------------------------------------------
// K0: weight pre-convert. wh_bf[768][768]; lin_bf[128][768] rows 98..127 zero.
// ---------------------------------------------------------------------------
__global__ void k_wprep(const float* __restrict__ gate_w, const float* __restrict__ lin_w,
                        ushort* __restrict__ wh_bf, ushort* __restrict__ lin_bf) {
  int r = blockIdx.x, t = threadIdx.x;
  if (r < NH) {
    float4 v = *(const float4*)(gate_w + (size_t)r * (2 * NH) + NH + t * 4);
    ushort4 h;
    h.x = f2bf(v.x); h.y = f2bf(v.y); h.z = f2bf(v.z); h.w = f2bf(v.w);
    *(ushort4*)&wh_bf[(size_t)r * NH + t * 4] = h;
  } else {
    int n = r - NH;  // 0..127
    ushort4 h; h.x = 0; h.y = 0; h.z = 0; h.w = 0;
    if (n < NP) {
      float4 v = *(const float4*)(lin_w + (size_t)n * NH + t * 4);
      h.x = f2bf(v.x); h.y = f2bf(v.y); h.z = f2bf(v.z); h.w = f2bf(v.w);
    }
    *(ushort4*)&lin_bf[(size_t)n * NH + t * 4] = h;
  }
}

// ---------------------------------------------------------------------------
// K1: fused hidden->bf16 convert + scores. 4 waves/block, 8 rows/wave.
// ---------------------------------------------------------------------------
__global__ void k_prep(const float* __restrict__ hidden, const float* __restrict__ aw,
                       const float* __restrict__ ab, ushort* __restrict__ hid_bf,
                       float* __restrict__ scores) {
  int wid = threadIdx.x >> 6, lane = threadIdx.x & 63;
  int rbase = blockIdx.x * 32 + wid * 8;
  float w0[12];
#pragma unroll
  for (int j = 0; j < 3; ++j) {
    float4 wv = *(const float4*)(aw + j * 256 + lane * 4);
    w0[4 * j] = wv.x; w0[4 * j + 1] = wv.y; w0[4 * j + 2] = wv.z; w0[4 * j + 3] = wv.w;
  }
  float abv = ab[0];
  for (int r = rbase; r < rbase + 8; ++r) {
    const float* row = hidden + (size_t)r * NH;
    float acc = 0.f;
#pragma unroll
    for (int j = 0; j < 3; ++j) {
      float4 v = *(const float4*)(row + j * 256 + lane * 4);
      acc += v.x * w0[4 * j] + v.y * w0[4 * j + 1] + v.z * w0[4 * j + 2] + v.w * w0[4 * j + 3];
      ushort4 h;
      h.x = f2bf(v.x); h.y = f2bf(v.y); h.z = f2bf(v.z); h.w = f2bf(v.w);
      *(ushort4*)&hid_bf[(size_t)r * NH + j * 256 + lane * 4] = h;
    }
#pragma unroll
    for (int off = 32; off; off >>= 1) acc += __shfl_xor(acc, off);
    if (lane == 0) scores[r] = acc + abv;
  }
}

// ---------------------------------------------------------------------------
// K2: per-batch cue_len, softmax max m[b] and denom l[b]
// ---------------------------------------------------------------------------
__global__ void k_stats(const int* __restrict__ mask, const float* __restrict__ scores,
                        int* __restrict__ cue, float* __restrict__ mout,
                        float* __restrict__ lout) {
  int b = blockIdx.x, t = threadIdx.x;
  int lane = t & 63, w = t >> 6;
  __shared__ float red[4];
  __shared__ int redi[4];
  __shared__ int cue_s;

  int sm = 0;
#pragma unroll
  for (int i = 0; i < 4; ++i) sm += mask[b * NS + t + 256 * i];
#pragma unroll
  for (int off = 32; off; off >>= 1) sm += __shfl_xor(sm, off);
  if (lane == 0) redi[w] = sm;
  __syncthreads();
  if (t == 0) {
    int tot = redi[0] + redi[1] + redi[2] + redi[3];
    tot = min(max(tot, 1), NS);
    cue_s = tot;
    cue[b] = tot;
  }
  __syncthreads();
  int cl = cue_s;

  float mx = -1e30f;
#pragma unroll
  for (int i = 0; i < 4; ++i) {
    int s = t + 256 * i;
    if (s < cl) mx = fmaxf(mx, scores[b * NS + s]);
  }
#pragma unroll
  for (int off = 32; off; off >>= 1) mx = fmaxf(mx, __shfl_xor(mx, off));
  if (lane == 0) red[w] = mx;
  __syncthreads();
  float m = fmaxf(fmaxf(red[0], red[1]), fmaxf(red[2], red[3]));
  __syncthreads();

  float sum = 0.f;
#pragma unroll
  for (int i = 0; i < 4; ++i) {
    int s = t + 256 * i;
    if (s < cl) sum += __expf(scores[b * NS + s] - m);
  }
#pragma unroll
  for (int off = 32; off; off >>= 1) sum += __shfl_xor(sum, off);
  if (lane == 0) red[w] = sum;
  __syncthreads();
  if (t == 0) {
    mout[b] = m;
    lout[b] = red[0] + red[1] + red[2] + red[3];
  }
}

// ---------------------------------------------------------------------------
// K3: s_x[b,h] from bf16 hidden. 192 thr: 4 cols each.
// ---------------------------------------------------------------------------
__global__ void k_sx(const ushort* __restrict__ hid_bf, const float* __restrict__ scores,
                     const int* __restrict__ cue, const float* __restrict__ m,
                     const float* __restrict__ l, float* __restrict__ sx) {
  int b = blockIdx.y, ch = blockIdx.x, t = threadIdx.x;
  int s0 = ch * 64;
  int cl = cue[b];
  if (s0 >= cl) return;
  __shared__ float w[64];
  if (t < 64) {
    int s = s0 + t;
    float wv = 0.f;
    if (s < cl) wv = __expf(scores[b * NS + s] - m[b]) / l[b];
    w[t] = wv;
  }
  __syncthreads();
  float4 a; a.x = 0.f; a.y = 0.f; a.z = 0.f; a.w = 0.f;
  const ushort* base = hid_bf + ((size_t)(b * NS + s0)) * NH;
  for (int s = 0; s < 64; ++s) {
    float ws = w[s];
    ushort4 v = *(const ushort4*)(base + s * NH + t * 4);
    a.x = fmaf(ws, bf2f(v.x), a.x);
    a.y = fmaf(ws, bf2f(v.y), a.y);
    a.z = fmaf(ws, bf2f(v.z), a.z);
    a.w = fmaf(ws, bf2f(v.w), a.w);
  }
  float* dst = sx + b * NH + t * 4;
  atomicAdd(dst + 0, a.x);
  atomicAdd(dst + 1, a.y);
  atomicAdd(dst + 2, a.z);
  atomicAdd(dst + 3, a.w);
}

// ---------------------------------------------------------------------------
// K4: g1[b,o] = dot(s_x[b,:], gate_w[o, 0:768])  grid (6 ogroups, 32 b)
// ---------------------------------------------------------------------------
__global__ void k_g1(const float* __restrict__ sx, const float* __restrict__ gate_w,
                     float* __restrict__ g1) {
  int b = blockIdx.y, og = blockIdx.x, t = threadIdx.x;
  __shared__ float sl[NH];
  if (t < 192) *(float4*)&sl[t * 4] = *(const float4*)(sx + b * NH + t * 4);
  __syncthreads();
  int w = t >> 6, lane = t & 63;
#pragma unroll 4
  for (int j = 0; j < 32; ++j) {
    int o = og * 128 + w * 32 + j;
    const float* gr = gate_w + (size_t)o * (2 * NH);
    float acc = 0.f;
#pragma unroll
    for (int q = 0; q < 3; ++q) {
      float4 gv = *(const float4*)(gr + q * 256 + lane * 4);
      float4 sv = *(const float4*)(&sl[q * 256 + lane * 4]);
      acc += gv.x * sv.x + gv.y * sv.y + gv.z * sv.z + gv.w * sv.w;
    }
#pragma unroll
    for (int off = 32; off; off >>= 1) acc += __shfl_xor(acc, off);
    if (lane == 0) g1[b * NH + o] = acc;
  }
}

// ---------------------------------------------------------------------------
// K5: g2 GEMM + gate epilogue -> hs_bf.  128x192 tile, BK=32, dbuf LDS 40KB,
// 2-phase pipeline (STAGE next buf -> compute cur -> barrier), 4 blocks/CU
// (4 x 40960 = 163840 B = full LDS), grid 1024 fully co-resident.
// Wave (of 4): 64 rows x 96 cols = 4x6 16x16 frags.
// XCD swizzle: xcd=bid&7 owns mt[32*xcd..+31] x 4 nt, nt-inner for A L2 reuse.
// ---------------------------------------------------------------------------
__global__ __launch_bounds__(256, 4) void k_gemm1(
    const ushort* __restrict__ hid_bf, const ushort* __restrict__ wh_bf,
    const float* __restrict__ gate_b, const float* __restrict__ sx,
    const float* __restrict__ g1, const int* __restrict__ cue,
    ushort* __restrict__ hs_bf) {
  __shared__ ushort As[2][128 * 32];
  __shared__ ushort Bs[2][192 * 32];
  const int t = threadIdx.x;
  const int lane = t & 63, wid = t >> 6;
  const int half = lane >> 4, r16 = lane & 15;

  const int bid = blockIdx.x;
  const int xcd = bid & 7, i = bid >> 3;
  const int nt = i & 3, mt = xcd * 32 + (i >> 2);
  const int row0 = mt * 128, col0 = nt * 192;

  // staging chunks: A 512 (2/thread), B 768 (3/thread); chunk c: n=c>>2, kq=c&3
  const int c0 = t, c1 = t + 256, c2 = t + 512;
  const ushort* gA0 = hid_bf + (size_t)(row0 + (c0 >> 2)) * NH + (c0 & 3) * 8;
  const ushort* gA1 = hid_bf + (size_t)(row0 + (c1 >> 2)) * NH + (c1 & 3) * 8;
  const ushort* gB0 = wh_bf + (size_t)(col0 + (c0 >> 2)) * NH + (c0 & 3) * 8;
  const ushort* gB1 = wh_bf + (size_t)(col0 + (c1 >> 2)) * NH + (c1 & 3) * 8;
  const ushort* gB2 = wh_bf + (size_t)(col0 + (c2 >> 2)) * NH + (c2 & 3) * 8;

  const int wm = wid >> 1, wn = wid & 1;
  f32x4 acc[4][6];
#pragma unroll
  for (int mf = 0; mf < 4; ++mf)
#pragma unroll
    for (int nf = 0; nf < 6; ++nf) acc[mf][nf] = (f32x4)0.f;

#define STAGE1(BUF, KS)                                  \
  {                                                      \
    const int k0_ = (KS) * 32;                           \
    gload16(gA0 + k0_, &As[BUF][c0 * 8]);                \
    gload16(gA1 + k0_, &As[BUF][c1 * 8]);                \
    gload16(gB0 + k0_, &Bs[BUF][c0 * 8]);                \
    gload16(gB1 + k0_, &Bs[BUF][c1 * 8]);                \
    gload16(gB2 + k0_, &Bs[BUF][c2 * 8]);                \
  }

#define COMPUTE1(BUF)                                                             \
  {                                                                               \
    short8 af[4], bfr[6];                                                         \
    _Pragma("unroll") for (int mf = 0; mf < 4; ++mf)                              \
        af[mf] = *(const short8*)&As[BUF][(wm * 64 + mf * 16 + r16) * 32 + half * 8]; \
    _Pragma("unroll") for (int nf = 0; nf < 6; ++nf)                              \
        bfr[nf] = *(const short8*)&Bs[BUF][(wn * 96 + nf * 16 + r16) * 32 + half * 8]; \
    _Pragma("unroll") for (int nf = 0; nf < 6; ++nf)                              \
        _Pragma("unroll") for (int mf = 0; mf < 4; ++mf)                          \
            acc[mf][nf] = __builtin_amdgcn_mfma_f32_16x16x32_bf16(af[mf], bfr[nf], \
                                                                  acc[mf][nf], 0, 0, 0); \
  }

  STAGE1(0, 0);
  __syncthreads();  // vmcnt drained by compiler before barrier: buf0 ready
#pragma unroll 1
  for (int ks2 = 0; ks2 < 12; ++ks2) {
    const int ks = ks2 * 2;
    STAGE1(1, ks + 1);   // loads fly while computing buf0
    COMPUTE1(0);
    __syncthreads();     // buf1 ready; all reads of buf0 done
    if (ks + 2 < 24) STAGE1(0, ks + 2);
    COMPUTE1(1);
    __syncthreads();
  }

  // gate epilogue
  const int b = mt >> 3;
  const int cl = cue[b];
#pragma unroll
  for (int nf = 0; nf < 6; ++nf) {
    int col = col0 + wn * 96 + nf * 16 + r16;
    float g1v = g1[b * NH + col];
    float sxv = sx[b * NH + col];
    float gbv = gate_b[col];
#pragma unroll
    for (int mf = 0; mf < 4; ++mf) {
#pragma unroll
      for (int p = 0; p < 4; ++p) {
        int grow = row0 + wm * 64 + mf * 16 + half * 4 + p;
        float x = bf2f(hid_bf[(size_t)grow * NH + col]);
        float gl = g1v + acc[mf][nf][p] + gbv;
        float g = 1.f / (1.f + __expf(-gl));
        float fused = g * sxv + (1.f - g) * x;
        float hs = x + (((grow & 1023) < cl) ? fused : 0.f);
        hs_bf[(size_t)grow * NH + col] = f2bf(hs);
      }
    }
  }
#undef STAGE1
#undef COMPUTE1
}

// ---------------------------------------------------------------------------
// K6: out = clip(sigmoid(hs_bf @ lin_bf^T + lin_b)). 64-row tiles x 512
// blocks (2/CU), BK=32, dbuf 24KB, same 2-phase pipeline.
// Wave (of 4): 16 rows x 112 cols = 1x7 frags.
// ---------------------------------------------------------------------------
__global__ __launch_bounds__(256, 4) void k_gemm2(
    const ushort* __restrict__ hs_bf, const ushort* __restrict__ lin_bf,
    const float* __restrict__ lin_b, float* __restrict__ out) {
  __shared__ ushort As[2][64 * 32];
  __shared__ ushort Bs[2][128 * 32];
  const int t = threadIdx.x;
  const int lane = t & 63, wid = t >> 6;
  const int half = lane >> 4, r16 = lane & 15;
  const int row0 = blockIdx.x * 64;

  const int cA = t;                    // A: 256 chunks, 1/thread
  const int cB0 = t, cB1 = t + 256;    // B: 512 chunks (128 rows), 2/thread
  const ushort* gA = hs_bf + (size_t)(row0 + (cA >> 2)) * NH + (cA & 3) * 8;
  const ushort* gB0 = lin_bf + (size_t)(cB0 >> 2) * NH + (cB0 & 3) * 8;
  const ushort* gB1 = lin_bf + (size_t)(cB1 >> 2) * NH + (cB1 & 3) * 8;

  f32x4 acc[7];
#pragma unroll
  for (int nf = 0; nf < 7; ++nf) acc[nf] = (f32x4)0.f;

#define STAGE2(BUF, KS)                                  \
  {                                                      \
    const int k0_ = (KS) * 32;                           \
    gload16(gA + k0_, &As[BUF][cA * 8]);                 \
    gload16(gB0 + k0_, &Bs[BUF][cB0 * 8]);               \
    gload16(gB1 + k0_, &Bs[BUF][cB1 * 8]);               \
  }

#define COMPUTE2(BUF)                                                          \
  {                                                                            \
    short8 a = *(const short8*)&As[BUF][(wid * 16 + r16) * 32 + half * 8];     \
    _Pragma("unroll") for (int nf = 0; nf < 7; ++nf) {                         \
      short8 bv = *(const short8*)&Bs[BUF][(nf * 16 + r16) * 32 + half * 8];   \
      acc[nf] = __builtin_amdgcn_mfma_f32_16x16x32_bf16(a, bv, acc[nf], 0, 0, 0); \
    }                                                                          \
  }

  STAGE2(0, 0);
  __syncthreads();
#pragma unroll 1
  for (int ks2 = 0; ks2 < 12; ++ks2) {
    const int ks = ks2 * 2;
    STAGE2(1, ks + 1);
    COMPUTE2(0);
    __syncthreads();
    if (ks + 2 < 24) STAGE2(0, ks + 2);
    COMPUTE2(1);
    __syncthreads();
  }

#pragma unroll
  for (int nf = 0; nf < 7; ++nf) {
    int col = nf * 16 + r16;
    bool valid = col < NP;
    float lbv = valid ? lin_b[col] : 0.f;
#pragma unroll
    for (int p = 0; p < 4; ++p) {
      int grow = row0 + wid * 16 + half * 4 + p;
      float v = acc[nf][p] + lbv;
      v = 1.f / (1.f + __expf(-v));
      v = fminf(fmaxf(v, 1e-7f), 1.f - 1e-7f);
      if (valid) out[(size_t)grow * NP + col] = v;
    }
  }
#undef STAGE2
#undef COMPUTE2
}

// ---------------------------------------------------------------------------
extern "C" void kernel_launch(void* const* d_in, const int* in_sizes, int n_in,
                              void* d_out, int out_size, void* d_ws, size_t ws_size,
                              hipStream_t stream) {
  const float* hidden = (const float*)d_in[0];
  // d_in[1] = batch_subject_ids: unused by the reference
  const int* mask = (const int*)d_in[2];
  const float* attn_w = (const float*)d_in[3];
  const float* attn_b = (const float*)d_in[4];
  const float* gate_w = (const float*)d_in[5];
  const float* gate_b = (const float*)d_in[6];
  const float* lin_w = (const float*)d_in[7];
  const float* lin_b = (const float*)d_in[8];
  float* out = (float*)d_out;

  // ws layout (floats): [cue:32i][m:32][l:32][scores:32768][sx:24576][g1:24576]
  // then (ushort, 16B-aligned): wh_bf[768*768] lin_bf[128*768]
  //                             hid_bf[32768*768] hs_bf[32768*768]  (~103 MB)
  float* F = (float*)d_ws;
  int* cue = (int*)F;
  float* m = F + 32;
  float* l = F + 64;
  float* scores = F + 96;
  float* sx = scores + NB * NS;
  float* g1 = sx + NB * NH;
  ushort* wh_bf = (ushort*)(g1 + NB * NH);
  ushort* lin_bf = wh_bf + (size_t)NH * NH;
  ushort* hid_bf = lin_bf + (size_t)128 * NH;
  ushort* hs_bf = hid_bf + (size_t)NB * NS * NH;

  hipMemsetAsync(sx, 0, NB * NH * sizeof(float), stream);
  k_wprep<<<896, 192, 0, stream>>>(gate_w, lin_w, wh_bf, lin_bf);
  k_prep<<<1024, 256, 0, stream>>>(hidden, attn_w, attn_b, hid_bf, scores);
  k_stats<<<NB, 256, 0, stream>>>(mask, scores, cue, m, l);
  k_sx<<<dim3(16, NB), 192, 0, stream>>>(hid_bf, scores, cue, m, l, sx);
  k_g1<<<dim3(6, NB), 256, 0, stream>>>(sx, gate_w, g1);
  k_gemm1<<<1024, 256, 0, stream>>>(hid_bf, wh_bf, gate_b, sx, g1, cue, hs_bf);
  k_gemm2<<<512, 256, 0, stream>>>(hs_bf, lin_bf, lin_b, out);
}

// Round 8
// 344.682 us; speedup vs baseline: 1.1022x; 1.1022x over previous
//
#include <hip/hip_runtime.h>
#include <hip/hip_bf16.h>
#include <cstdint>

// Shapes (fixed by the problem)
#define NB 32
#define NS 1024
#define NH 768
#define NP 98

typedef __attribute__((ext_vector_type(8))) short short8;
typedef __attribute__((ext_vector_type(4))) float f32x4;

static __device__ __forceinline__ ushort f2bf(float f) {
  uint32_t u = __builtin_bit_cast(uint32_t, f);
  u += 0x7fff + ((u >> 16) & 1);  // RNE
  return (ushort)(u >> 16);
}
static __device__ __forceinline__ float bf2f(ushort h) {
  uint32_t u = ((uint32_t)h) << 16;
  return __builtin_bit_cast(float, u);
}
// async global->LDS 16B (per-lane global src, wave-uniform LDS base + lane*16)
static __device__ __forceinline__ void gload16(const ushort* g, ushort* l) {
  __builtin_amdgcn_global_load_lds((const __attribute__((address_space(1))) uint32_t*)g,
                                   (__attribute__((address_space(3))) uint32_t*)l, 16, 0, 0);
}

// ---------------------------------------------------------------------------
// K0: weight pre-convert. wh_bf[768][768] (gate_wh); gs_bf[768][768] (gate_ws);
// lin_bf[128][768] rows 98..127 zero.  Grid 1664 x 192.
// ---------------------------------------------------------------------------
__global__ void k_wprep(const float* __restrict__ gate_w, const float* __restrict__ lin_w,
                        ushort* __restrict__ wh_bf, ushort* __restrict__ gs_bf,
                        ushort* __restrict__ lin_bf) {
  int r = blockIdx.x, t = threadIdx.x;
  if (r < NH) {
    float4 v = *(const float4*)(gate_w + (size_t)r * (2 * NH) + NH + t * 4);
    ushort4 h;
    h.x = f2bf(v.x); h.y = f2bf(v.y); h.z = f2bf(v.z); h.w = f2bf(v.w);
    *(ushort4*)&wh_bf[(size_t)r * NH + t * 4] = h;
  } else if (r < 2 * NH) {
    int n = r - NH;
    float4 v = *(const float4*)(gate_w + (size_t)n * (2 * NH) + t * 4);
    ushort4 h;
    h.x = f2bf(v.x); h.y = f2bf(v.y); h.z = f2bf(v.z); h.w = f2bf(v.w);
    *(ushort4*)&gs_bf[(size_t)n * NH + t * 4] = h;
  } else {
    int n = r - 2 * NH;  // 0..127
    ushort4 h; h.x = 0; h.y = 0; h.z = 0; h.w = 0;
    if (n < NP) {
      float4 v = *(const float4*)(lin_w + (size_t)n * NH + t * 4);
      h.x = f2bf(v.x); h.y = f2bf(v.y); h.z = f2bf(v.z); h.w = f2bf(v.w);
    }
    *(ushort4*)&lin_bf[(size_t)n * NH + t * 4] = h;
  }
}

// ---------------------------------------------------------------------------
// K1: fused hidden->bf16 convert + scores. 4 waves/block, 8 rows/wave.
// ---------------------------------------------------------------------------
__global__ void k_prep(const float* __restrict__ hidden, const float* __restrict__ aw,
                       const float* __restrict__ ab, ushort* __restrict__ hid_bf,
                       float* __restrict__ scores) {
  int wid = threadIdx.x >> 6, lane = threadIdx.x & 63;
  int rbase = blockIdx.x * 32 + wid * 8;
  float w0[12];
#pragma unroll
  for (int j = 0; j < 3; ++j) {
    float4 wv = *(const float4*)(aw + j * 256 + lane * 4);
    w0[4 * j] = wv.x; w0[4 * j + 1] = wv.y; w0[4 * j + 2] = wv.z; w0[4 * j + 3] = wv.w;
  }
  float abv = ab[0];
  for (int r = rbase; r < rbase + 8; ++r) {
    const float* row = hidden + (size_t)r * NH;
    float acc = 0.f;
#pragma unroll
    for (int j = 0; j < 3; ++j) {
      float4 v = *(const float4*)(row + j * 256 + lane * 4);
      acc += v.x * w0[4 * j] + v.y * w0[4 * j + 1] + v.z * w0[4 * j + 2] + v.w * w0[4 * j + 3];
      ushort4 h;
      h.x = f2bf(v.x); h.y = f2bf(v.y); h.z = f2bf(v.z); h.w = f2bf(v.w);
      *(ushort4*)&hid_bf[(size_t)r * NH + j * 256 + lane * 4] = h;
    }
#pragma unroll
    for (int off = 32; off; off >>= 1) acc += __shfl_xor(acc, off);
    if (lane == 0) scores[r] = acc + abv;
  }
}

// ---------------------------------------------------------------------------
// K2: per-batch cue_len, softmax max m[b] and denom l[b]
// ---------------------------------------------------------------------------
__global__ void k_stats(const int* __restrict__ mask, const float* __restrict__ scores,
                        int* __restrict__ cue, float* __restrict__ mout,
                        float* __restrict__ lout) {
  int b = blockIdx.x, t = threadIdx.x;
  int lane = t & 63, w = t >> 6;
  __shared__ float red[4];
  __shared__ int redi[4];
  __shared__ int cue_s;

  int sm = 0;
#pragma unroll
  for (int i = 0; i < 4; ++i) sm += mask[b * NS + t + 256 * i];
#pragma unroll
  for (int off = 32; off; off >>= 1) sm += __shfl_xor(sm, off);
  if (lane == 0) redi[w] = sm;
  __syncthreads();
  if (t == 0) {
    int tot = redi[0] + redi[1] + redi[2] + redi[3];
    tot = min(max(tot, 1), NS);
    cue_s = tot;
    cue[b] = tot;
  }
  __syncthreads();
  int cl = cue_s;

  float mx = -1e30f;
#pragma unroll
  for (int i = 0; i < 4; ++i) {
    int s = t + 256 * i;
    if (s < cl) mx = fmaxf(mx, scores[b * NS + s]);
  }
#pragma unroll
  for (int off = 32; off; off >>= 1) mx = fmaxf(mx, __shfl_xor(mx, off));
  if (lane == 0) red[w] = mx;
  __syncthreads();
  float m = fmaxf(fmaxf(red[0], red[1]), fmaxf(red[2], red[3]));
  __syncthreads();

  float sum = 0.f;
#pragma unroll
  for (int i = 0; i < 4; ++i) {
    int s = t + 256 * i;
    if (s < cl) sum += __expf(scores[b * NS + s] - m);
  }
#pragma unroll
  for (int off = 32; off; off >>= 1) sum += __shfl_xor(sum, off);
  if (lane == 0) red[w] = sum;
  __syncthreads();
  if (t == 0) {
    mout[b] = m;
    lout[b] = red[0] + red[1] + red[2] + red[3];
  }
}

// ---------------------------------------------------------------------------
// K3: s_x[b,h] from bf16 hidden. 192 thr: 4 cols each.
// ---------------------------------------------------------------------------
__global__ void k_sx(const ushort* __restrict__ hid_bf, const float* __restrict__ scores,
                     const int* __restrict__ cue, const float* __restrict__ m,
                     const float* __restrict__ l, float* __restrict__ sx) {
  int b = blockIdx.y, ch = blockIdx.x, t = threadIdx.x;
  int s0 = ch * 64;
  int cl = cue[b];
  if (s0 >= cl) return;
  __shared__ float w[64];
  if (t < 64) {
    int s = s0 + t;
    float wv = 0.f;
    if (s < cl) wv = __expf(scores[b * NS + s] - m[b]) / l[b];
    w[t] = wv;
  }
  __syncthreads();
  float4 a; a.x = 0.f; a.y = 0.f; a.z = 0.f; a.w = 0.f;
  const ushort* base = hid_bf + ((size_t)(b * NS + s0)) * NH;
  for (int s = 0; s < 64; ++s) {
    float ws = w[s];
    ushort4 v = *(const ushort4*)(base + s * NH + t * 4);
    a.x = fmaf(ws, bf2f(v.x), a.x);
    a.y = fmaf(ws, bf2f(v.y), a.y);
    a.z = fmaf(ws, bf2f(v.z), a.z);
    a.w = fmaf(ws, bf2f(v.w), a.w);
  }
  float* dst = sx + b * NH + t * 4;
  atomicAdd(dst + 0, a.x);
  atomicAdd(dst + 1, a.y);
  atomicAdd(dst + 2, a.z);
  atomicAdd(dst + 3, a.w);
}

// ---------------------------------------------------------------------------
// K4: g1[b,o] = dot(s_x[b,:], gate_ws_bf[o,:])  grid (6 ogroups, 32 b).
// Per-lane sx slice (12 f32) hoisted to registers; gs read as bf16.
// ---------------------------------------------------------------------------
__global__ void k_g1(const float* __restrict__ sx, const ushort* __restrict__ gs_bf,
                     float* __restrict__ g1) {
  int b = blockIdx.y, og = blockIdx.x, t = threadIdx.x;
  int w = t >> 6, lane = t & 63;
  float sreg[12];
#pragma unroll
  for (int e = 0; e < 12; ++e) sreg[e] = sx[b * NH + lane * 12 + e];
#pragma unroll 4
  for (int j = 0; j < 32; ++j) {
    int o = og * 128 + w * 32 + j;
    const ushort* gr = gs_bf + (size_t)o * NH + lane * 12;
    ushort us[12];
    *(ushort4*)&us[0] = *(const ushort4*)(gr);
    *(ushort4*)&us[4] = *(const ushort4*)(gr + 4);
    *(ushort4*)&us[8] = *(const ushort4*)(gr + 8);
    float acc = 0.f;
#pragma unroll
    for (int e = 0; e < 12; ++e) acc = fmaf(bf2f(us[e]), sreg[e], acc);
#pragma unroll
    for (int off = 32; off; off >>= 1) acc += __shfl_xor(acc, off);
    if (lane == 0) g1[b * NH + o] = acc;
  }
}

// ---------------------------------------------------------------------------
// K5: g2 GEMM + gate epilogue -> hs_bf.  128x192 tile, BK=32, dbuf LDS 40KB,
// 2-phase pipeline.  __launch_bounds__(256,3): reg budget ~170 ≥ 96 AGPR acc
// + ~64 VGPR -> NO SPILL (round-6 lesson: (256,4) spilled acc -> +160MB
// scratch traffic).  3 blocks/CU resident.
// Wave (of 4): 64 rows x 96 cols = 4x6 16x16 frags.
// XCD swizzle: xcd=bid&7 owns mt[32*xcd..+31] x 4 nt, nt-inner for A L2 reuse.
// ---------------------------------------------------------------------------
__global__ __launch_bounds__(256, 3) void k_gemm1(
    const ushort* __restrict__ hid_bf, const ushort* __restrict__ wh_bf,
    const float* __restrict__ gate_b, const float* __restrict__ sx,
    const float* __restrict__ g1, const int* __restrict__ cue,
    ushort* __restrict__ hs_bf) {
  __shared__ ushort As[2][128 * 32];
  __shared__ ushort Bs[2][192 * 32];
  const int t = threadIdx.x;
  const int lane = t & 63, wid = t >> 6;
  const int half = lane >> 4, r16 = lane & 15;

  const int bid = blockIdx.x;
  const int xcd = bid & 7, i = bid >> 3;
  const int nt = i & 3, mt = xcd * 32 + (i >> 2);
  const int row0 = mt * 128, col0 = nt * 192;

  // staging chunks: A 512 (2/thread), B 768 (3/thread); chunk c: n=c>>2, kq=c&3
  const int c0 = t, c1 = t + 256, c2 = t + 512;
  const ushort* gA0 = hid_bf + (size_t)(row0 + (c0 >> 2)) * NH + (c0 & 3) * 8;
  const ushort* gA1 = hid_bf + (size_t)(row0 + (c1 >> 2)) * NH + (c1 & 3) * 8;
  const ushort* gB0 = wh_bf + (size_t)(col0 + (c0 >> 2)) * NH + (c0 & 3) * 8;
  const ushort* gB1 = wh_bf + (size_t)(col0 + (c1 >> 2)) * NH + (c1 & 3) * 8;
  const ushort* gB2 = wh_bf + (size_t)(col0 + (c2 >> 2)) * NH + (c2 & 3) * 8;

  const int wm = wid >> 1, wn = wid & 1;
  f32x4 acc[4][6];
#pragma unroll
  for (int mf = 0; mf < 4; ++mf)
#pragma unroll
    for (int nf = 0; nf < 6; ++nf) acc[mf][nf] = (f32x4)0.f;

#define STAGE1(BUF, KS)                                  \
  {                                                      \
    const int k0_ = (KS) * 32;                           \
    gload16(gA0 + k0_, &As[BUF][c0 * 8]);                \
    gload16(gA1 + k0_, &As[BUF][c1 * 8]);                \
    gload16(gB0 + k0_, &Bs[BUF][c0 * 8]);                \
    gload16(gB1 + k0_, &Bs[BUF][c1 * 8]);                \
    gload16(gB2 + k0_, &Bs[BUF][c2 * 8]);                \
  }

#define COMPUTE1(BUF)                                                             \
  {                                                                               \
    short8 af[4], bfr[6];                                                         \
    _Pragma("unroll") for (int mf = 0; mf < 4; ++mf)                              \
        af[mf] = *(const short8*)&As[BUF][(wm * 64 + mf * 16 + r16) * 32 + half * 8]; \
    _Pragma("unroll") for (int nf = 0; nf < 6; ++nf)                              \
        bfr[nf] = *(const short8*)&Bs[BUF][(wn * 96 + nf * 16 + r16) * 32 + half * 8]; \
    _Pragma("unroll") for (int nf = 0; nf < 6; ++nf)                              \
        _Pragma("unroll") for (int mf = 0; mf < 4; ++mf)                          \
            acc[mf][nf] = __builtin_amdgcn_mfma_f32_16x16x32_bf16(af[mf], bfr[nf], \
                                                                  acc[mf][nf], 0, 0, 0); \
  }

  STAGE1(0, 0);
  __syncthreads();  // vmcnt drained by compiler before barrier: buf0 ready
#pragma unroll 1
  for (int ks2 = 0; ks2 < 12; ++ks2) {
    const int ks = ks2 * 2;
    STAGE1(1, ks + 1);   // loads fly while computing buf0
    COMPUTE1(0);
    __syncthreads();     // buf1 ready; all reads of buf0 done
    if (ks + 2 < 24) STAGE1(0, ks + 2);
    COMPUTE1(1);
    __syncthreads();
  }

  // gate epilogue
  const int b = mt >> 3;
  const int cl = cue[b];
#pragma unroll
  for (int nf = 0; nf < 6; ++nf) {
    int col = col0 + wn * 96 + nf * 16 + r16;
    float g1v = g1[b * NH + col];
    float sxv = sx[b * NH + col];
    float gbv = gate_b[col];
#pragma unroll
    for (int mf = 0; mf < 4; ++mf) {
#pragma unroll
      for (int p = 0; p < 4; ++p) {
        int grow = row0 + wm * 64 + mf * 16 + half * 4 + p;
        float x = bf2f(hid_bf[(size_t)grow * NH + col]);
        float gl = g1v + acc[mf][nf][p] + gbv;
        float g = 1.f / (1.f + __expf(-gl));
        float fused = g * sxv + (1.f - g) * x;
        float hs = x + (((grow & 1023) < cl) ? fused : 0.f);
        hs_bf[(size_t)grow * NH + col] = f2bf(hs);
      }
    }
  }
#undef STAGE1
#undef COMPUTE1
}

// ---------------------------------------------------------------------------
// K6: out = clip(sigmoid(hs_bf @ lin_bf^T + lin_b)). 64-row tiles x 512
// blocks, BK=32, dbuf 24KB, same 2-phase pipeline.
// Wave (of 4): 16 rows x 112 cols = 1x7 frags (28 acc regs: no spill risk).
// ---------------------------------------------------------------------------
__global__ __launch_bounds__(256, 4) void k_gemm2(
    const ushort* __restrict__ hs_bf, const ushort* __restrict__ lin_bf,
    const float* __restrict__ lin_b, float* __restrict__ out) {
  __shared__ ushort As[2][64 * 32];
  __shared__ ushort Bs[2][128 * 32];
  const int t = threadIdx.x;
  const int lane = t & 63, wid = t >> 6;
  const int half = lane >> 4, r16 = lane & 15;
  const int row0 = blockIdx.x * 64;

  const int cA = t;                    // A: 256 chunks, 1/thread
  const int cB0 = t, cB1 = t + 256;    // B: 512 chunks (128 rows), 2/thread
  const ushort* gA = hs_bf + (size_t)(row0 + (cA >> 2)) * NH + (cA & 3) * 8;
  const ushort* gB0 = lin_bf + (size_t)(cB0 >> 2) * NH + (cB0 & 3) * 8;
  const ushort* gB1 = lin_bf + (size_t)(cB1 >> 2) * NH + (cB1 & 3) * 8;

  f32x4 acc[7];
#pragma unroll
  for (int nf = 0; nf < 7; ++nf) acc[nf] = (f32x4)0.f;

#define STAGE2(BUF, KS)                                  \
  {                                                      \
    const int k0_ = (KS) * 32;                           \
    gload16(gA + k0_, &As[BUF][cA * 8]);                 \
    gload16(gB0 + k0_, &Bs[BUF][cB0 * 8]);               \
    gload16(gB1 + k0_, &Bs[BUF][cB1 * 8]);               \
  }

#define COMPUTE2(BUF)                                                          \
  {                                                                            \
    short8 a = *(const short8*)&As[BUF][(wid * 16 + r16) * 32 + half * 8];     \
    _Pragma("unroll") for (int nf = 0; nf < 7; ++nf) {                         \
      short8 bv = *(const short8*)&Bs[BUF][(nf * 16 + r16) * 32 + half * 8];   \
      acc[nf] = __builtin_amdgcn_mfma_f32_16x16x32_bf16(a, bv, acc[nf], 0, 0, 0); \
    }                                                                          \
  }

  STAGE2(0, 0);
  __syncthreads();
#pragma unroll 1
  for (int ks2 = 0; ks2 < 12; ++ks2) {
    const int ks = ks2 * 2;
    STAGE2(1, ks + 1);
    COMPUTE2(0);
    __syncthreads();
    if (ks + 2 < 24) STAGE2(0, ks + 2);
    COMPUTE2(1);
    __syncthreads();
  }

#pragma unroll
  for (int nf = 0; nf < 7; ++nf) {
    int col = nf * 16 + r16;
    bool valid = col < NP;
    float lbv = valid ? lin_b[col] : 0.f;
#pragma unroll
    for (int p = 0; p < 4; ++p) {
      int grow = row0 + wid * 16 + half * 4 + p;
      float v = acc[nf][p] + lbv;
      v = 1.f / (1.f + __expf(-v));
      v = fminf(fmaxf(v, 1e-7f), 1.f - 1e-7f);
      if (valid) out[(size_t)grow * NP + col] = v;
    }
  }
#undef STAGE2
#undef COMPUTE2
}

// ---------------------------------------------------------------------------
extern "C" void kernel_launch(void* const* d_in, const int* in_sizes, int n_in,
                              void* d_out, int out_size, void* d_ws, size_t ws_size,
                              hipStream_t stream) {
  const float* hidden = (const float*)d_in[0];
  // d_in[1] = batch_subject_ids: unused by the reference
  const int* mask = (const int*)d_in[2];
  const float* attn_w = (const float*)d_in[3];
  const float* attn_b = (const float*)d_in[4];
  const float* gate_w = (const float*)d_in[5];
  const float* gate_b = (const float*)d_in[6];
  const float* lin_w = (const float*)d_in[7];
  const float* lin_b = (const float*)d_in[8];
  float* out = (float*)d_out;

  // ws layout (floats): [cue:32i][m:32][l:32][scores:32768][sx:24576][g1:24576]
  // then (ushort, 16B-aligned): wh_bf[768*768] gs_bf[768*768] lin_bf[128*768]
  //                             hid_bf[32768*768] hs_bf[32768*768]  (~104 MB)
  float* F = (float*)d_ws;
  int* cue = (int*)F;
  float* m = F + 32;
  float* l = F + 64;
  float* scores = F + 96;
  float* sx = scores + NB * NS;
  float* g1 = sx + NB * NH;
  ushort* wh_bf = (ushort*)(g1 + NB * NH);
  ushort* gs_bf = wh_bf + (size_t)NH * NH;
  ushort* lin_bf = gs_bf + (size_t)NH * NH;
  ushort* hid_bf = lin_bf + (size_t)128 * NH;
  ushort* hs_bf = hid_bf + (size_t)NB * NS * NH;

  hipMemsetAsync(sx, 0, NB * NH * sizeof(float), stream);
  k_wprep<<<1664, 192, 0, stream>>>(gate_w, lin_w, wh_bf, gs_bf, lin_bf);
  k_prep<<<1024, 256, 0, stream>>>(hidden, attn_w, attn_b, hid_bf, scores);
  k_stats<<<NB, 256, 0, stream>>>(mask, scores, cue, m, l);
  k_sx<<<dim3(16, NB), 192, 0, stream>>>(hid_bf, scores, cue, m, l, sx);
  k_g1<<<dim3(6, NB), 256, 0, stream>>>(sx, gs_bf, g1);
  k_gemm1<<<1024, 256, 0, stream>>>(hid_bf, wh_bf, gate_b, sx, g1, cue, hs_bf);
  k_gemm2<<<512, 256, 0, stream>>>(hs_bf, lin_bf, lin_b, out);
}

// Round 9
// 290.441 us; speedup vs baseline: 1.3080x; 1.1868x over previous
//
#include <hip/hip_runtime.h>
#include <hip/hip_bf16.h>
#include <cstdint>

// Shapes (fixed by the problem)
#define NB 32
#define NS 1024
#define NH 768
#define NP 98

typedef __attribute__((ext_vector_type(8))) short short8;
typedef __attribute__((ext_vector_type(4))) float f32x4;

static __device__ __forceinline__ ushort f2bf(float f) {
  uint32_t u = __builtin_bit_cast(uint32_t, f);
  u += 0x7fff + ((u >> 16) & 1);  // RNE
  return (ushort)(u >> 16);
}
static __device__ __forceinline__ float bf2f(ushort h) {
  uint32_t u = ((uint32_t)h) << 16;
  return __builtin_bit_cast(float, u);
}
// async global->LDS 16B (per-lane global src, wave-uniform LDS base + lane*16)
static __device__ __forceinline__ void gload16(const ushort* g, ushort* l) {
  __builtin_amdgcn_global_load_lds((const __attribute__((address_space(1))) uint32_t*)g,
                                   (__attribute__((address_space(3))) uint32_t*)l, 16, 0, 0);
}

// ---------------------------------------------------------------------------
// K0: weight pre-convert. wh_bf[768][768] (gate_wh); gs_bf[768][768] (gate_ws);
// lin_bf[128][768] rows 98..127 zero.  Grid 1664 x 192.
// ---------------------------------------------------------------------------
__global__ void k_wprep(const float* __restrict__ gate_w, const float* __restrict__ lin_w,
                        ushort* __restrict__ wh_bf, ushort* __restrict__ gs_bf,
                        ushort* __restrict__ lin_bf) {
  int r = blockIdx.x, t = threadIdx.x;
  if (r < NH) {
    float4 v = *(const float4*)(gate_w + (size_t)r * (2 * NH) + NH + t * 4);
    ushort4 h;
    h.x = f2bf(v.x); h.y = f2bf(v.y); h.z = f2bf(v.z); h.w = f2bf(v.w);
    *(ushort4*)&wh_bf[(size_t)r * NH + t * 4] = h;
  } else if (r < 2 * NH) {
    int n = r - NH;
    float4 v = *(const float4*)(gate_w + (size_t)n * (2 * NH) + t * 4);
    ushort4 h;
    h.x = f2bf(v.x); h.y = f2bf(v.y); h.z = f2bf(v.z); h.w = f2bf(v.w);
    *(ushort4*)&gs_bf[(size_t)n * NH + t * 4] = h;
  } else {
    int n = r - 2 * NH;  // 0..127
    ushort4 h; h.x = 0; h.y = 0; h.z = 0; h.w = 0;
    if (n < NP) {
      float4 v = *(const float4*)(lin_w + (size_t)n * NH + t * 4);
      h.x = f2bf(v.x); h.y = f2bf(v.y); h.z = f2bf(v.z); h.w = f2bf(v.w);
    }
    *(ushort4*)&lin_bf[(size_t)n * NH + t * 4] = h;
  }
}

// ---------------------------------------------------------------------------
// K1: fused hidden->bf16 convert + scores. 4 waves/block, 8 rows/wave.
// ---------------------------------------------------------------------------
__global__ void k_prep(const float* __restrict__ hidden, const float* __restrict__ aw,
                       const float* __restrict__ ab, ushort* __restrict__ hid_bf,
                       float* __restrict__ scores) {
  int wid = threadIdx.x >> 6, lane = threadIdx.x & 63;
  int rbase = blockIdx.x * 32 + wid * 8;
  float w0[12];
#pragma unroll
  for (int j = 0; j < 3; ++j) {
    float4 wv = *(const float4*)(aw + j * 256 + lane * 4);
    w0[4 * j] = wv.x; w0[4 * j + 1] = wv.y; w0[4 * j + 2] = wv.z; w0[4 * j + 3] = wv.w;
  }
  float abv = ab[0];
  for (int r = rbase; r < rbase + 8; ++r) {
    const float* row = hidden + (size_t)r * NH;
    float acc = 0.f;
#pragma unroll
    for (int j = 0; j < 3; ++j) {
      float4 v = *(const float4*)(row + j * 256 + lane * 4);
      acc += v.x * w0[4 * j] + v.y * w0[4 * j + 1] + v.z * w0[4 * j + 2] + v.w * w0[4 * j + 3];
      ushort4 h;
      h.x = f2bf(v.x); h.y = f2bf(v.y); h.z = f2bf(v.z); h.w = f2bf(v.w);
      *(ushort4*)&hid_bf[(size_t)r * NH + j * 256 + lane * 4] = h;
    }
#pragma unroll
    for (int off = 32; off; off >>= 1) acc += __shfl_xor(acc, off);
    if (lane == 0) scores[r] = acc + abv;
  }
}

// ---------------------------------------------------------------------------
// K2: per-batch cue_len, softmax max m[b] and denom l[b]
// ---------------------------------------------------------------------------
__global__ void k_stats(const int* __restrict__ mask, const float* __restrict__ scores,
                        int* __restrict__ cue, float* __restrict__ mout,
                        float* __restrict__ lout) {
  int b = blockIdx.x, t = threadIdx.x;
  int lane = t & 63, w = t >> 6;
  __shared__ float red[4];
  __shared__ int redi[4];
  __shared__ int cue_s;

  int sm = 0;
#pragma unroll
  for (int i = 0; i < 4; ++i) sm += mask[b * NS + t + 256 * i];
#pragma unroll
  for (int off = 32; off; off >>= 1) sm += __shfl_xor(sm, off);
  if (lane == 0) redi[w] = sm;
  __syncthreads();
  if (t == 0) {
    int tot = redi[0] + redi[1] + redi[2] + redi[3];
    tot = min(max(tot, 1), NS);
    cue_s = tot;
    cue[b] = tot;
  }
  __syncthreads();
  int cl = cue_s;

  float mx = -1e30f;
#pragma unroll
  for (int i = 0; i < 4; ++i) {
    int s = t + 256 * i;
    if (s < cl) mx = fmaxf(mx, scores[b * NS + s]);
  }
#pragma unroll
  for (int off = 32; off; off >>= 1) mx = fmaxf(mx, __shfl_xor(mx, off));
  if (lane == 0) red[w] = mx;
  __syncthreads();
  float m = fmaxf(fmaxf(red[0], red[1]), fmaxf(red[2], red[3]));
  __syncthreads();

  float sum = 0.f;
#pragma unroll
  for (int i = 0; i < 4; ++i) {
    int s = t + 256 * i;
    if (s < cl) sum += __expf(scores[b * NS + s] - m);
  }
#pragma unroll
  for (int off = 32; off; off >>= 1) sum += __shfl_xor(sum, off);
  if (lane == 0) red[w] = sum;
  __syncthreads();
  if (t == 0) {
    mout[b] = m;
    lout[b] = red[0] + red[1] + red[2] + red[3];
  }
}

// ---------------------------------------------------------------------------
// K3: s_x[b,h] from bf16 hidden. 192 thr: 4 cols each.
// ---------------------------------------------------------------------------
__global__ void k_sx(const ushort* __restrict__ hid_bf, const float* __restrict__ scores,
                     const int* __restrict__ cue, const float* __restrict__ m,
                     const float* __restrict__ l, float* __restrict__ sx) {
  int b = blockIdx.y, ch = blockIdx.x, t = threadIdx.x;
  int s0 = ch * 64;
  int cl = cue[b];
  if (s0 >= cl) return;
  __shared__ float w[64];
  if (t < 64) {
    int s = s0 + t;
    float wv = 0.f;
    if (s < cl) wv = __expf(scores[b * NS + s] - m[b]) / l[b];
    w[t] = wv;
  }
  __syncthreads();
  float4 a; a.x = 0.f; a.y = 0.f; a.z = 0.f; a.w = 0.f;
  const ushort* base = hid_bf + ((size_t)(b * NS + s0)) * NH;
  for (int s = 0; s < 64; ++s) {
    float ws = w[s];
    ushort4 v = *(const ushort4*)(base + s * NH + t * 4);
    a.x = fmaf(ws, bf2f(v.x), a.x);
    a.y = fmaf(ws, bf2f(v.y), a.y);
    a.z = fmaf(ws, bf2f(v.z), a.z);
    a.w = fmaf(ws, bf2f(v.w), a.w);
  }
  float* dst = sx + b * NH + t * 4;
  atomicAdd(dst + 0, a.x);
  atomicAdd(dst + 1, a.y);
  atomicAdd(dst + 2, a.z);
  atomicAdd(dst + 3, a.w);
}

// ---------------------------------------------------------------------------
// K4: g1[b,o] = dot(s_x[b,:], gate_ws_bf[o,:])  grid (6 ogroups, 32 b).
// ---------------------------------------------------------------------------
__global__ void k_g1(const float* __restrict__ sx, const ushort* __restrict__ gs_bf,
                     float* __restrict__ g1) {
  int b = blockIdx.y, og = blockIdx.x, t = threadIdx.x;
  int w = t >> 6, lane = t & 63;
  float sreg[12];
#pragma unroll
  for (int e = 0; e < 12; ++e) sreg[e] = sx[b * NH + lane * 12 + e];
#pragma unroll 4
  for (int j = 0; j < 32; ++j) {
    int o = og * 128 + w * 32 + j;
    const ushort* gr = gs_bf + (size_t)o * NH + lane * 12;
    ushort us[12];
    *(ushort4*)&us[0] = *(const ushort4*)(gr);
    *(ushort4*)&us[4] = *(const ushort4*)(gr + 4);
    *(ushort4*)&us[8] = *(const ushort4*)(gr + 8);
    float acc = 0.f;
#pragma unroll
    for (int e = 0; e < 12; ++e) acc = fmaf(bf2f(us[e]), sreg[e], acc);
#pragma unroll
    for (int off = 32; off; off >>= 1) acc += __shfl_xor(acc, off);
    if (lane == 0) g1[b * NH + o] = acc;
  }
}

// ---------------------------------------------------------------------------
// K5: g2 GEMM + gate epilogue -> hs_bf.
// Tile 128x128, BK=32, 3-deep LDS buffers (48KB), counted-vmcnt single-barrier
// pipeline (T4: never drain vmcnt to 0 in-loop; prefetch 2 slabs ahead).
// Each thread issues exactly 4 gload16/stage -> steady wait = vmcnt(4).
// Source-kq XOR swizzle (rule 21: linear LDS dest, pre-swizzled global src,
// same XOR on ds_read): kq ^= (row&3)^((row>>2)&3) -> 2-way banks (free).
// __launch_bounds__(256,3): ~126 regs < 170 budget, no spill; 3 blocks/CU.
// Wave (of 4, 2x2): 64x64 = 4x4 16x16 frags (64 acc regs).
// XCD swizzle: 1536 blocks = 8 xcd x (32 mt x 6 nt), nt-inner for A L2 reuse.
// ---------------------------------------------------------------------------
__global__ __launch_bounds__(256, 3) void k_gemm1(
    const ushort* __restrict__ hid_bf, const ushort* __restrict__ wh_bf,
    const float* __restrict__ gate_b, const float* __restrict__ sx,
    const float* __restrict__ g1, const int* __restrict__ cue,
    ushort* __restrict__ hs_bf) {
  __shared__ ushort As[3][128 * 32];
  __shared__ ushort Bs[3][128 * 32];
  const int t = threadIdx.x;
  const int lane = t & 63, wid = t >> 6;
  const int half = lane >> 4, r16 = lane & 15;

  const int bid = blockIdx.x;
  const int xcd = bid & 7, i = bid >> 3;   // i in 0..191
  const int nt = i % 6, mt = xcd * 32 + i / 6;
  const int row0 = mt * 128, col0 = nt * 128;

  // staging: A chunks t, t+256; B chunks t, t+256. chunk c: row=c>>2, kq=c&3.
  // source kq-xor (uniform per thread for both its chunks):
  const int xs = ((t >> 2) & 3) ^ ((t >> 4) & 3);
  const int kqs = ((t & 3) ^ xs) * 8;
  const ushort* gA0 = hid_bf + (size_t)(row0 + (t >> 2)) * NH + kqs;
  const ushort* gA1 = hid_bf + (size_t)(row0 + 64 + (t >> 2)) * NH + kqs;
  const ushort* gB0 = wh_bf + (size_t)(col0 + (t >> 2)) * NH + kqs;
  const ushort* gB1 = wh_bf + (size_t)(col0 + 64 + (t >> 2)) * NH + kqs;
  // read-side half-xor (row base is mult of 16 -> depends only on r16):
  const int xr = (r16 & 3) ^ ((r16 >> 2) & 3);

  const int wm = wid >> 1, wn = wid & 1;
  f32x4 acc[4][4];
#pragma unroll
  for (int mf = 0; mf < 4; ++mf)
#pragma unroll
    for (int nf = 0; nf < 4; ++nf) acc[mf][nf] = (f32x4)0.f;

#define STAGE1(BUF, KS)                                   \
  {                                                       \
    const int k0_ = (KS) * 32;                            \
    gload16(gA0 + k0_, &As[BUF][t * 8]);                  \
    gload16(gA1 + k0_, &As[BUF][(t + 256) * 8]);          \
    gload16(gB0 + k0_, &Bs[BUF][t * 8]);                  \
    gload16(gB1 + k0_, &Bs[BUF][(t + 256) * 8]);          \
  }

#define COMPUTE1(BUF)                                                               \
  {                                                                                 \
    short8 af[4], bfr[4];                                                           \
    _Pragma("unroll") for (int mf = 0; mf < 4; ++mf)                                \
        af[mf] = *(const short8*)&As[BUF][(wm * 64 + mf * 16 + r16) * 32 +          \
                                          ((half ^ xr) * 8)];                       \
    _Pragma("unroll") for (int nf = 0; nf < 4; ++nf)                                \
        bfr[nf] = *(const short8*)&Bs[BUF][(wn * 64 + nf * 16 + r16) * 32 +         \
                                           ((half ^ xr) * 8)];                      \
    _Pragma("unroll") for (int nf = 0; nf < 4; ++nf)                                \
        _Pragma("unroll") for (int mf = 0; mf < 4; ++mf)                            \
            acc[mf][nf] = __builtin_amdgcn_mfma_f32_16x16x32_bf16(af[mf], bfr[nf],  \
                                                                  acc[mf][nf], 0, 0, 0); \
  }

  // counted wait (never 0 in-loop) + raw barrier; sched fence per rule #18
#define WAITBAR(N)                                       \
  asm volatile("s_waitcnt vmcnt(" #N ")" ::: "memory");  \
  __builtin_amdgcn_s_barrier();                          \
  __builtin_amdgcn_sched_barrier(0);

  STAGE1(0, 0);
  STAGE1(1, 1);
  // slabs 0..20: full triple iterations (stage slab+2 every slab)
#pragma unroll 1
  for (int tt = 0; tt < 7; ++tt) {
    const int s0_ = tt * 3;
    WAITBAR(4); COMPUTE1(0); STAGE1(2, s0_ + 2);
    WAITBAR(4); COMPUTE1(1); STAGE1(0, s0_ + 3);
    WAITBAR(4); COMPUTE1(2); STAGE1(1, s0_ + 4);
  }
  // peeled tail: slab 21 (stage 23), 22, 23
  WAITBAR(4); COMPUTE1(0); STAGE1(2, 23);
  WAITBAR(4); COMPUTE1(1);
  WAITBAR(0); COMPUTE1(2);

  // gate epilogue
  const int b = mt >> 3;
  const int cl = cue[b];
#pragma unroll
  for (int nf = 0; nf < 4; ++nf) {
    int col = col0 + wn * 64 + nf * 16 + r16;
    float g1v = g1[b * NH + col];
    float sxv = sx[b * NH + col];
    float gbv = gate_b[col];
#pragma unroll
    for (int mf = 0; mf < 4; ++mf) {
#pragma unroll
      for (int p = 0; p < 4; ++p) {
        int grow = row0 + wm * 64 + mf * 16 + half * 4 + p;
        float x = bf2f(hid_bf[(size_t)grow * NH + col]);
        float gl = g1v + acc[mf][nf][p] + gbv;
        float g = 1.f / (1.f + __expf(-gl));
        float fused = g * sxv + (1.f - g) * x;
        float hs = x + (((grow & 1023) < cl) ? fused : 0.f);
        hs_bf[(size_t)grow * NH + col] = f2bf(hs);
      }
    }
  }
#undef STAGE1
#undef COMPUTE1
}

// ---------------------------------------------------------------------------
// K6: out = clip(sigmoid(hs_bf @ lin_bf^T + lin_b)). 64x128 tiles, 512 blocks,
// same counted-vmcnt 3-buffer pipeline (3 loads/thread/stage -> vmcnt(3)).
// Wave (of 4): 16 rows x 128 cols = 1x8 frags (32 acc regs). LDS 36KB.
// ---------------------------------------------------------------------------
__global__ __launch_bounds__(256, 4) void k_gemm2(
    const ushort* __restrict__ hs_bf, const ushort* __restrict__ lin_bf,
    const float* __restrict__ lin_b, float* __restrict__ out) {
  __shared__ ushort As[3][64 * 32];
  __shared__ ushort Bs[3][128 * 32];
  const int t = threadIdx.x;
  const int lane = t & 63, wid = t >> 6;
  const int half = lane >> 4, r16 = lane & 15;
  const int row0 = blockIdx.x * 64;

  const int xs = ((t >> 2) & 3) ^ ((t >> 4) & 3);
  const int kqs = ((t & 3) ^ xs) * 8;
  const ushort* gA = hs_bf + (size_t)(row0 + (t >> 2)) * NH + kqs;       // 256 chunks
  const ushort* gB0 = lin_bf + (size_t)(t >> 2) * NH + kqs;              // rows 0..63
  const ushort* gB1 = lin_bf + (size_t)(64 + (t >> 2)) * NH + kqs;       // rows 64..127
  const int xr = (r16 & 3) ^ ((r16 >> 2) & 3);

  f32x4 acc[8];
#pragma unroll
  for (int nf = 0; nf < 8; ++nf) acc[nf] = (f32x4)0.f;

#define STAGE2(BUF, KS)                                   \
  {                                                       \
    const int k0_ = (KS) * 32;                            \
    gload16(gA + k0_, &As[BUF][t * 8]);                   \
    gload16(gB0 + k0_, &Bs[BUF][t * 8]);                  \
    gload16(gB1 + k0_, &Bs[BUF][(t + 256) * 8]);          \
  }

#define COMPUTE2(BUF)                                                               \
  {                                                                                 \
    short8 a = *(const short8*)&As[BUF][(wid * 16 + r16) * 32 + ((half ^ xr) * 8)]; \
    _Pragma("unroll") for (int nf = 0; nf < 8; ++nf) {                              \
      short8 bv = *(const short8*)&Bs[BUF][(nf * 16 + r16) * 32 + ((half ^ xr) * 8)]; \
      acc[nf] = __builtin_amdgcn_mfma_f32_16x16x32_bf16(a, bv, acc[nf], 0, 0, 0);   \
    }                                                                               \
  }

#define WAITBAR2(N)                                      \
  asm volatile("s_waitcnt vmcnt(" #N ")" ::: "memory");  \
  __builtin_amdgcn_s_barrier();                          \
  __builtin_amdgcn_sched_barrier(0);

  STAGE2(0, 0);
  STAGE2(1, 1);
#pragma unroll 1
  for (int tt = 0; tt < 7; ++tt) {
    const int s0_ = tt * 3;
    WAITBAR2(3); COMPUTE2(0); STAGE2(2, s0_ + 2);
    WAITBAR2(3); COMPUTE2(1); STAGE2(0, s0_ + 3);
    WAITBAR2(3); COMPUTE2(2); STAGE2(1, s0_ + 4);
  }
  WAITBAR2(3); COMPUTE2(0); STAGE2(2, 23);
  WAITBAR2(3); COMPUTE2(1);
  WAITBAR2(0); COMPUTE2(2);

#pragma unroll
  for (int nf = 0; nf < 8; ++nf) {
    int col = nf * 16 + r16;
    bool valid = col < NP;
    float lbv = valid ? lin_b[col] : 0.f;
#pragma unroll
    for (int p = 0; p < 4; ++p) {
      int grow = row0 + wid * 16 + half * 4 + p;
      float v = acc[nf][p] + lbv;
      v = 1.f / (1.f + __expf(-v));
      v = fminf(fmaxf(v, 1e-7f), 1.f - 1e-7f);
      if (valid) out[(size_t)grow * NP + col] = v;
    }
  }
#undef STAGE2
#undef COMPUTE2
#undef WAITBAR2
}

// ---------------------------------------------------------------------------
extern "C" void kernel_launch(void* const* d_in, const int* in_sizes, int n_in,
                              void* d_out, int out_size, void* d_ws, size_t ws_size,
                              hipStream_t stream) {
  const float* hidden = (const float*)d_in[0];
  // d_in[1] = batch_subject_ids: unused by the reference
  const int* mask = (const int*)d_in[2];
  const float* attn_w = (const float*)d_in[3];
  const float* attn_b = (const float*)d_in[4];
  const float* gate_w = (const float*)d_in[5];
  const float* gate_b = (const float*)d_in[6];
  const float* lin_w = (const float*)d_in[7];
  const float* lin_b = (const float*)d_in[8];
  float* out = (float*)d_out;

  // ws layout (floats): [cue:32i][m:32][l:32][scores:32768][sx:24576][g1:24576]
  // then (ushort, 16B-aligned): wh_bf[768*768] gs_bf[768*768] lin_bf[128*768]
  //                             hid_bf[32768*768] hs_bf[32768*768]  (~104 MB)
  float* F = (float*)d_ws;
  int* cue = (int*)F;
  float* m = F + 32;
  float* l = F + 64;
  float* scores = F + 96;
  float* sx = scores + NB * NS;
  float* g1 = sx + NB * NH;
  ushort* wh_bf = (ushort*)(g1 + NB * NH);
  ushort* gs_bf = wh_bf + (size_t)NH * NH;
  ushort* lin_bf = gs_bf + (size_t)NH * NH;
  ushort* hid_bf = lin_bf + (size_t)128 * NH;
  ushort* hs_bf = hid_bf + (size_t)NB * NS * NH;

  hipMemsetAsync(sx, 0, NB * NH * sizeof(float), stream);
  k_wprep<<<1664, 192, 0, stream>>>(gate_w, lin_w, wh_bf, gs_bf, lin_bf);
  k_prep<<<1024, 256, 0, stream>>>(hidden, attn_w, attn_b, hid_bf, scores);
  k_stats<<<NB, 256, 0, stream>>>(mask, scores, cue, m, l);
  k_sx<<<dim3(16, NB), 192, 0, stream>>>(hid_bf, scores, cue, m, l, sx);
  k_g1<<<dim3(6, NB), 256, 0, stream>>>(sx, gs_bf, g1);
  k_gemm1<<<1536, 256, 0, stream>>>(hid_bf, wh_bf, gate_b, sx, g1, cue, hs_bf);
  k_gemm2<<<512, 256, 0, stream>>>(hs_bf, lin_bf, lin_b, out);
}